// Round 3
// baseline (90.882 us; speedup 1.0000x reference)
//
#include <hip/hip_runtime.h>

// score[e] = dot(h_src[src_idx[e]], h_dst[dst_idx[e]]), D = 128.
//
// Random gather over 102 MB tables is L2-miss-path bound (~3.5 TB/s on 303 MB
// of miss traffic). Fix: bucket-sort edges by src row bucket (idx>>8, 128 KB
// of rows per bucket) so src reads become L2-resident; XCD-chunked block
// swizzle keeps each XCD's live window ~0.5 MB. 4 dispatches:
//   hist -> scan -> scatter(pairs+perm) -> main gather-dot.
// Output written to out[perm[p]] (original edge order) => deterministic.

#define FEAT_D 128
#define EPG 4       // edges per 32-lane group in the dot kernel
#define BSHIFT 8    // bucket = src_idx >> 8  (256 rows = 128 KB per bucket)
#define NBMAX 512   // max buckets supported (N <= 131072)
#define NBLK_H 128  // blocks for hist/scatter

// ---------------- pass 1: per-block histograms (no global atomics) ----------
__global__ __launch_bounds__(256) void hist_kernel(const int* __restrict__ src_idx,
                                                   int E, int nb, int epb,
                                                   int* __restrict__ counts_blk) {
    __shared__ int h[NBMAX];
    for (int t = threadIdx.x; t < nb; t += 256) h[t] = 0;
    __syncthreads();
    int start = blockIdx.x * epb;
    int end   = min(start + epb, E);
    for (int e = start + threadIdx.x; e < end; e += 256)
        atomicAdd(&h[src_idx[e] >> BSHIFT], 1);
    __syncthreads();
    int* row = counts_blk + blockIdx.x * NBMAX;
    for (int t = threadIdx.x; t < nb; t += 256) row[t] = h[t];
}

// ---------------- pass 2: sum block histograms + exclusive prefix -----------
__global__ __launch_bounds__(NBMAX) void scan_kernel(const int* __restrict__ counts_blk,
                                                     int nb, int* __restrict__ gcur) {
    __shared__ int s[NBMAX];
    int t = threadIdx.x;
    int v = 0;
    if (t < nb)
        for (int b = 0; b < NBLK_H; ++b) v += counts_blk[b * NBMAX + t];
    s[t] = v;
    __syncthreads();
    for (int off = 1; off < NBMAX; off <<= 1) {
        int u = (t >= off) ? s[t - off] : 0;
        __syncthreads();
        s[t] += u;
        __syncthreads();
    }
    if (t < nb) gcur[t] = s[t] - v;   // exclusive prefix -> running cursor
}

// ---------------- pass 3: scatter edges into bucket order -------------------
__global__ __launch_bounds__(256) void scatter_kernel(const int* __restrict__ src_idx,
                                                      const int* __restrict__ dst_idx,
                                                      int E, int nb, int epb,
                                                      int* __restrict__ gcur,
                                                      int2* __restrict__ pair,
                                                      int*  __restrict__ perm) {
    __shared__ int h[NBMAX];
    __shared__ int base[NBMAX];
    for (int t = threadIdx.x; t < nb; t += 256) h[t] = 0;
    __syncthreads();
    int start = blockIdx.x * epb;
    int end   = min(start + epb, E);
    for (int e = start + threadIdx.x; e < end; e += 256)
        atomicAdd(&h[src_idx[e] >> BSHIFT], 1);
    __syncthreads();
    for (int t = threadIdx.x; t < nb; t += 256) {
        int c = h[t];
        base[t] = c ? atomicAdd(&gcur[t], c) : 0;
        h[t] = 0;  // reuse as local cursor
    }
    __syncthreads();
    for (int e = start + threadIdx.x; e < end; e += 256) {
        int s = src_idx[e];
        int b = s >> BSHIFT;
        int p = base[b] + atomicAdd(&h[b], 1);
        pair[p] = make_int2(s, dst_idx[e]);
        perm[p] = e;
    }
}

// ---------------- pass 4: gather-dot over sorted edges ----------------------
__global__ __launch_bounds__(256) void edge_dot_sorted(const float* __restrict__ h_src,
                                                       const float* __restrict__ h_dst,
                                                       const int2* __restrict__ pair,
                                                       const int*  __restrict__ perm,
                                                       float* __restrict__ out,
                                                       int E, int G) {
    // XCD-chunked bijective swizzle (m204): XCD x processes a contiguous
    // range of sorted edges -> per-XCD L2 sees a narrow src-row window.
    int orig = blockIdx.x;
    int q = G >> 3, r = G & 7;
    int xcd = orig & 7, slot = orig >> 3;
    int wg = (xcd < r ? xcd * (q + 1) : r * (q + 1) + (xcd - r) * q) + slot;

    int group = wg * 8 + (int)(threadIdx.x >> 5);  // 8 groups of 32 lanes/block
    int lane  = (int)(threadIdx.x & 31);
    int p0 = group * EPG;
    if (p0 >= E) return;

    int2 pr[EPG];
    int  po[EPG];
    #pragma unroll
    for (int i = 0; i < EPG; ++i) {
        int p = p0 + i;
        int pc = (p < E) ? p : (E - 1);
        pr[i] = pair[pc];
        po[i] = perm[pc];
    }

    float4 a[EPG], b[EPG];
    #pragma unroll
    for (int i = 0; i < EPG; ++i)
        a[i] = reinterpret_cast<const float4*>(h_src + (long)pr[i].x * FEAT_D)[lane];
    #pragma unroll
    for (int i = 0; i < EPG; ++i)
        b[i] = reinterpret_cast<const float4*>(h_dst + (long)pr[i].y * FEAT_D)[lane];

    #pragma unroll
    for (int i = 0; i < EPG; ++i) {
        float s = a[i].x * b[i].x + a[i].y * b[i].y + a[i].z * b[i].z + a[i].w * b[i].w;
        #pragma unroll
        for (int off = 16; off >= 1; off >>= 1)
            s += __shfl_xor(s, off);
        if (lane == 0) out[po[i]] = s;
    }
}

// ---------------- fallback: direct (round-2) kernel -------------------------
__global__ __launch_bounds__(256) void edge_dot_kernel(const float* __restrict__ h_src,
                                                       const float* __restrict__ h_dst,
                                                       const int*   __restrict__ src_idx,
                                                       const int*   __restrict__ dst_idx,
                                                       float*       __restrict__ out,
                                                       int E) {
    long gtid = (long)blockIdx.x * blockDim.x + threadIdx.x;
    int group = (int)(gtid >> 5);
    int lane  = (int)(threadIdx.x & 31);
    int e0 = group * EPG;
    if (e0 >= E) return;

    int sidx[EPG], tidx[EPG];
    #pragma unroll
    for (int i = 0; i < EPG; ++i) {
        int e = e0 + i;
        int ec = (e < E) ? e : (E - 1);
        sidx[i] = src_idx[ec];
        tidx[i] = dst_idx[ec];
    }
    float4 a[EPG], b[EPG];
    #pragma unroll
    for (int i = 0; i < EPG; ++i)
        a[i] = reinterpret_cast<const float4*>(h_src + (long)sidx[i] * FEAT_D)[lane];
    #pragma unroll
    for (int i = 0; i < EPG; ++i)
        b[i] = reinterpret_cast<const float4*>(h_dst + (long)tidx[i] * FEAT_D)[lane];
    #pragma unroll
    for (int i = 0; i < EPG; ++i) {
        float s = a[i].x * b[i].x + a[i].y * b[i].y + a[i].z * b[i].z + a[i].w * b[i].w;
        #pragma unroll
        for (int off = 16; off >= 1; off >>= 1)
            s += __shfl_xor(s, off);
        if (lane == 0 && e0 + i < E) out[e0 + i] = s;
    }
}

extern "C" void kernel_launch(void* const* d_in, const int* in_sizes, int n_in,
                              void* d_out, int out_size, void* d_ws, size_t ws_size,
                              hipStream_t stream) {
    const float* h_src   = (const float*)d_in[0];
    const float* h_dst   = (const float*)d_in[1];
    const int*   src_idx = (const int*)d_in[2];
    const int*   dst_idx = (const int*)d_in[3];
    float* out = (float*)d_out;

    int E = in_sizes[2];
    int N = in_sizes[0] / FEAT_D;
    int nb = (N + ((1 << BSHIFT) - 1)) >> BSHIFT;

    // workspace layout
    size_t off_pair   = 0;
    size_t off_perm   = off_pair + (size_t)E * 8;
    size_t off_cblk   = off_perm + (size_t)E * 4;
    size_t off_gcur   = off_cblk + (size_t)NBLK_H * NBMAX * 4;
    size_t needed     = off_gcur + (size_t)NBMAX * 4;

    long groups = ((long)E + EPG - 1) / EPG;

    if (nb > NBMAX || ws_size < needed) {
        // fallback: direct gather
        long total_threads = groups * 32;
        long grid = (total_threads + 255) / 256;
        edge_dot_kernel<<<(unsigned)grid, 256, 0, stream>>>(h_src, h_dst, src_idx, dst_idx, out, E);
        return;
    }

    char* ws = (char*)d_ws;
    int2* pair       = (int2*)(ws + off_pair);
    int*  perm       = (int*) (ws + off_perm);
    int*  counts_blk = (int*) (ws + off_cblk);
    int*  gcur       = (int*) (ws + off_gcur);

    int epb = (E + NBLK_H - 1) / NBLK_H;

    hist_kernel<<<NBLK_H, 256, 0, stream>>>(src_idx, E, nb, epb, counts_blk);
    scan_kernel<<<1, NBMAX, 0, stream>>>(counts_blk, nb, gcur);
    scatter_kernel<<<NBLK_H, 256, 0, stream>>>(src_idx, dst_idx, E, nb, epb, gcur, pair, perm);

    int G = (int)((groups + 7) / 8);  // 8 groups per 256-thread block
    edge_dot_sorted<<<G, 256, 0, stream>>>(h_src, h_dst, pair, perm, out, E, G);
}